// Round 1
// baseline (338.978 us; speedup 1.0000x reference)
//
#include <hip/hip_runtime.h>
#include <cstdint>

#define BB 2
#define SS 2048
#define DD 1024
#define HH 16
#define HDIM 64
#define MM (BB*SS)      // 4096
#define N3 (3*DD)       // 3072

typedef __attribute__((ext_vector_type(4))) float f32x4;
typedef __attribute__((ext_vector_type(8))) __bf16 bf16x8;

static __device__ __forceinline__ unsigned short f2bf(float f) {
  union { float f; unsigned int u; } v; v.f = f;
  unsigned int u = v.u;
  u += 0x7fffu + ((u >> 16) & 1u);   // round-nearest-even
  return (unsigned short)(u >> 16);
}

static __device__ __forceinline__ uint4 pack8f(const float4 a, const float4 b) {
  union { unsigned short us[8]; uint4 v; } pk;
  pk.us[0] = f2bf(a.x); pk.us[1] = f2bf(a.y); pk.us[2] = f2bf(a.z); pk.us[3] = f2bf(a.w);
  pk.us[4] = f2bf(b.x); pk.us[5] = f2bf(b.y); pk.us[6] = f2bf(b.z); pk.us[7] = f2bf(b.w);
  return pk.v;
}

// ---------------------------------------------------------------------------
// QKV GEMM: C[4096,3072] = x[4096,1024] @ W_w[3072,1024]^T + W_b
// epilogue scatters to q/k/v [b,h,s,hd] bf16
// 128x128 tile, BK=32, 4 waves each 64x64 (4x4 frags of 16x16x32 bf16 MFMA)
// ---------------------------------------------------------------------------
__global__ __launch_bounds__(256) void gemm_qkv(
    const float* __restrict__ x, const float* __restrict__ Ww,
    const float* __restrict__ Wb,
    unsigned short* __restrict__ qb, unsigned short* __restrict__ kb,
    unsigned short* __restrict__ vb) {
  __shared__ __align__(16) unsigned short As[128 * 40];  // +8 pad: breaks 8-way bank conflict
  __shared__ __align__(16) unsigned short Bs[128 * 40];
  const int t = threadIdx.x;
  const int l = t & 63, w = t >> 6;
  const int wr = w >> 1, wc = w & 1;
  const int m0 = blockIdx.y * 128, n0 = blockIdx.x * 128;
  f32x4 acc[4][4] = {};

  for (int kt = 0; kt < DD; kt += 32) {
    __syncthreads();
    #pragma unroll
    for (int it = 0; it < 2; ++it) {
      const int row = it * 64 + (t >> 2);
      const int c0 = (t & 3) * 8;
      const float4* ga = (const float4*)(x  + (size_t)(m0 + row) * DD + kt + c0);
      const float4* gb = (const float4*)(Ww + (size_t)(n0 + row) * DD + kt + c0);
      *(uint4*)&As[row * 40 + c0] = pack8f(ga[0], ga[1]);
      *(uint4*)&Bs[row * 40 + c0] = pack8f(gb[0], gb[1]);
    }
    __syncthreads();
    bf16x8 a[4], b[4];
    #pragma unroll
    for (int i = 0; i < 4; ++i) {
      a[i] = __builtin_bit_cast(bf16x8, *(const uint4*)&As[(wr * 64 + i * 16 + (l & 15)) * 40 + (l >> 4) * 8]);
      b[i] = __builtin_bit_cast(bf16x8, *(const uint4*)&Bs[(wc * 64 + i * 16 + (l & 15)) * 40 + (l >> 4) * 8]);
    }
    #pragma unroll
    for (int i = 0; i < 4; ++i)
      #pragma unroll
      for (int j = 0; j < 4; ++j)
        acc[i][j] = __builtin_amdgcn_mfma_f32_16x16x32_bf16(a[i], b[j], acc[i][j], 0, 0, 0);
  }

  // epilogue: C/D layout col=lane&15, row=(lane>>4)*4+reg (HW-verified mapping)
  #pragma unroll
  for (int i = 0; i < 4; ++i)
    #pragma unroll
    for (int j = 0; j < 4; ++j)
      #pragma unroll
      for (int r = 0; r < 4; ++r) {
        const int row = m0 + wr * 64 + i * 16 + (l >> 4) * 4 + r;
        const int col = n0 + wc * 64 + j * 16 + (l & 15);
        const float v = acc[i][j][r] + Wb[col];
        const int bidx = row >> 11;         // row / 2048
        const int srow = row & 2047;
        const int which = col >> 10;        // 0=q 1=k 2=v
        const int cc = col & 1023;
        const int head = cc >> 6;
        const int hd = cc & 63;
        const size_t idx = ((size_t)((bidx * HH + head) * SS + srow)) * HDIM + hd;
        const unsigned short bv = f2bf(v);
        if (which == 0)      qb[idx] = bv;
        else if (which == 1) kb[idx] = bv;
        else                 vb[idx] = bv;
      }
}

// ---------------------------------------------------------------------------
// Attention: per block = one (b,h) pair x one 64-row q-tile. 4 waves, each
// owns 16 q-rows. Two passes over 32 k-tiles of 64:
//   pass1: online max m / denom l (exact softmax stats)
//   pass2: recompute S, write normalized P to attn_weights, O += P @ V
// ---------------------------------------------------------------------------
__global__ __launch_bounds__(256) void attn_kernel(
    const unsigned short* __restrict__ qb,
    const unsigned short* __restrict__ kb,
    const unsigned short* __restrict__ vb,
    unsigned short* __restrict__ ob,
    float* __restrict__ attn_out) {
  __shared__ __align__(16) unsigned short Ks[64 * 72];   // +8 pad
  __shared__ __align__(16) unsigned short Vt[64 * 72];   // V transposed [hd][kv]
  __shared__ __align__(16) unsigned short Ps[4 * 16 * 72];
  const int t = threadIdx.x;
  const int l = t & 63, w = t >> 6;
  const int bh = blockIdx.y;
  const int q0 = blockIdx.x * 64;
  const size_t base = (size_t)bh * SS * HDIM;
  const float sc = 0.03125f;   // 1/sqrt(1024)

  // Q fragments straight from global (one-time): lane needs Q[w*16+(l&15)][k..k+8]
  bf16x8 qa[2];
  #pragma unroll
  for (int kc = 0; kc < 2; ++kc)
    qa[kc] = __builtin_bit_cast(bf16x8,
        *(const uint4*)(qb + base + (size_t)(q0 + w * 16 + (l & 15)) * HDIM + kc * 32 + (l >> 4) * 8));

  float mrow[4], lrow[4];
  #pragma unroll
  for (int r = 0; r < 4; ++r) { mrow[r] = -1e30f; lrow[r] = 0.f; }

  // -------- pass 1: softmax stats --------
  for (int kt = 0; kt < SS; kt += 64) {
    __syncthreads();
    {
      const int row = t >> 2, c0 = (t & 3) * 16;
      const uint4* g = (const uint4*)(kb + base + (size_t)(kt + row) * HDIM + c0);
      uint4* d = (uint4*)&Ks[row * 72 + c0];
      d[0] = g[0]; d[1] = g[1];
    }
    __syncthreads();
    f32x4 sf[4] = {};
    #pragma unroll
    for (int kc = 0; kc < 2; ++kc)
      #pragma unroll
      for (int n = 0; n < 4; ++n) {
        bf16x8 kf = __builtin_bit_cast(bf16x8, *(const uint4*)&Ks[(n * 16 + (l & 15)) * 72 + kc * 32 + (l >> 4) * 8]);
        sf[n] = __builtin_amdgcn_mfma_f32_16x16x32_bf16(qa[kc], kf, sf[n], 0, 0, 0);
      }
    #pragma unroll
    for (int r = 0; r < 4; ++r) {
      float tm = fmaxf(fmaxf(sf[0][r], sf[1][r]), fmaxf(sf[2][r], sf[3][r])) * sc;
      #pragma unroll
      for (int off = 1; off < 16; off <<= 1) tm = fmaxf(tm, __shfl_xor(tm, off));
      const float mn = fmaxf(mrow[r], tm);
      float ssum = __expf(sf[0][r] * sc - mn) + __expf(sf[1][r] * sc - mn)
                 + __expf(sf[2][r] * sc - mn) + __expf(sf[3][r] * sc - mn);
      #pragma unroll
      for (int off = 1; off < 16; off <<= 1) ssum += __shfl_xor(ssum, off);
      lrow[r] = lrow[r] * __expf(mrow[r] - mn) + ssum;
      mrow[r] = mn;
    }
  }
  float rl[4];
  #pragma unroll
  for (int r = 0; r < 4; ++r) rl[r] = 1.0f / lrow[r];

  // -------- pass 2: write P, accumulate O --------
  f32x4 of[4] = {};
  unsigned short* Pw = &Ps[w * 16 * 72];
  for (int kt = 0; kt < SS; kt += 64) {
    __syncthreads();
    {
      const int row = t >> 2, c0 = (t & 3) * 16;
      const uint4* g = (const uint4*)(kb + base + (size_t)(kt + row) * HDIM + c0);
      uint4* d = (uint4*)&Ks[row * 72 + c0];
      d[0] = g[0]; d[1] = g[1];
      const unsigned short* gv = vb + base + (size_t)(kt + row) * HDIM + c0;
      #pragma unroll
      for (int e = 0; e < 16; ++e) Vt[(c0 + e) * 72 + row] = gv[e];  // transpose into LDS
    }
    __syncthreads();
    f32x4 sf[4] = {};
    #pragma unroll
    for (int kc = 0; kc < 2; ++kc)
      #pragma unroll
      for (int n = 0; n < 4; ++n) {
        bf16x8 kf = __builtin_bit_cast(bf16x8, *(const uint4*)&Ks[(n * 16 + (l & 15)) * 72 + kc * 32 + (l >> 4) * 8]);
        sf[n] = __builtin_amdgcn_mfma_f32_16x16x32_bf16(qa[kc], kf, sf[n], 0, 0, 0);
      }
    #pragma unroll
    for (int n = 0; n < 4; ++n)
      #pragma unroll
      for (int r = 0; r < 4; ++r) {
        const float p = __expf(sf[n][r] * sc - mrow[r]) * rl[r];
        const int lr = (l >> 4) * 4 + r;
        attn_out[((size_t)bh * SS + (q0 + w * 16 + lr)) * SS + kt + n * 16 + (l & 15)] = p;
        Pw[lr * 72 + n * 16 + (l & 15)] = f2bf(p);
      }
    __syncthreads();
    #pragma unroll
    for (int kc = 0; kc < 2; ++kc) {
      bf16x8 pa = __builtin_bit_cast(bf16x8, *(const uint4*)&Pw[(l & 15) * 72 + kc * 32 + (l >> 4) * 8]);
      #pragma unroll
      for (int n = 0; n < 4; ++n) {
        bf16x8 vf = __builtin_bit_cast(bf16x8, *(const uint4*)&Vt[(n * 16 + (l & 15)) * 72 + kc * 32 + (l >> 4) * 8]);
        of[n] = __builtin_amdgcn_mfma_f32_16x16x32_bf16(pa, vf, of[n], 0, 0, 0);
      }
    }
  }
  // O -> ob as [b, s, h*64+c] bf16
  const int bidx = bh >> 4, h_ = bh & 15;
  #pragma unroll
  for (int n = 0; n < 4; ++n)
    #pragma unroll
    for (int r = 0; r < 4; ++r) {
      const int lr = (l >> 4) * 4 + r;
      const int srow = q0 + w * 16 + lr;
      const int col = h_ * 64 + n * 16 + (l & 15);
      ob[((size_t)bidx * SS + srow) * DD + col] = f2bf(of[n][r]);
    }
}

// ---------------------------------------------------------------------------
// Proj GEMM: y[4096,1024] = ob @ proj_w^T + proj_b + x   (fp32 out)
// ---------------------------------------------------------------------------
__global__ __launch_bounds__(256) void gemm_proj(
    const unsigned short* __restrict__ ob, const float* __restrict__ pw,
    const float* __restrict__ pb, const float* __restrict__ x,
    float* __restrict__ y) {
  __shared__ __align__(16) unsigned short As[128 * 40];
  __shared__ __align__(16) unsigned short Bs[128 * 40];
  const int t = threadIdx.x;
  const int l = t & 63, w = t >> 6;
  const int wr = w >> 1, wc = w & 1;
  const int m0 = blockIdx.y * 128, n0 = blockIdx.x * 128;
  f32x4 acc[4][4] = {};

  for (int kt = 0; kt < DD; kt += 32) {
    __syncthreads();
    #pragma unroll
    for (int it = 0; it < 2; ++it) {
      const int row = it * 64 + (t >> 2);
      const int c0 = (t & 3) * 8;
      *(uint4*)&As[row * 40 + c0] = *(const uint4*)(ob + (size_t)(m0 + row) * DD + kt + c0);
      const float4* gb = (const float4*)(pw + (size_t)(n0 + row) * DD + kt + c0);
      *(uint4*)&Bs[row * 40 + c0] = pack8f(gb[0], gb[1]);
    }
    __syncthreads();
    bf16x8 a[4], b[4];
    #pragma unroll
    for (int i = 0; i < 4; ++i) {
      a[i] = __builtin_bit_cast(bf16x8, *(const uint4*)&As[(wr * 64 + i * 16 + (l & 15)) * 40 + (l >> 4) * 8]);
      b[i] = __builtin_bit_cast(bf16x8, *(const uint4*)&Bs[(wc * 64 + i * 16 + (l & 15)) * 40 + (l >> 4) * 8]);
    }
    #pragma unroll
    for (int i = 0; i < 4; ++i)
      #pragma unroll
      for (int j = 0; j < 4; ++j)
        acc[i][j] = __builtin_amdgcn_mfma_f32_16x16x32_bf16(a[i], b[j], acc[i][j], 0, 0, 0);
  }
  #pragma unroll
  for (int i = 0; i < 4; ++i)
    #pragma unroll
    for (int j = 0; j < 4; ++j)
      #pragma unroll
      for (int r = 0; r < 4; ++r) {
        const int row = m0 + wr * 64 + i * 16 + (l >> 4) * 4 + r;
        const int col = n0 + wc * 64 + j * 16 + (l & 15);
        const size_t idx = (size_t)row * DD + col;
        y[idx] = acc[i][j][r] + pb[col] + x[idx];
      }
}

// ---------------------------------------------------------------------------
// LayerNorm over d=1024 per row
// ---------------------------------------------------------------------------
__global__ __launch_bounds__(256) void ln_kernel(
    const float* __restrict__ y, const float* __restrict__ gamma,
    const float* __restrict__ beta, float* __restrict__ out) {
  const int row = blockIdx.x;
  const int t = threadIdx.x;
  const float4 v = ((const float4*)(y + (size_t)row * DD))[t];
  float s  = v.x + v.y + v.z + v.w;
  float s2 = v.x * v.x + v.y * v.y + v.z * v.z + v.w * v.w;
  #pragma unroll
  for (int off = 1; off < 64; off <<= 1) { s += __shfl_xor(s, off); s2 += __shfl_xor(s2, off); }
  __shared__ float red[8];
  const int l = t & 63, w = t >> 6;
  if (l == 0) { red[w] = s; red[4 + w] = s2; }
  __syncthreads();
  s  = red[0] + red[1] + red[2] + red[3];
  s2 = red[4] + red[5] + red[6] + red[7];
  const float mu = s * (1.0f / DD);
  const float var = s2 * (1.0f / DD) - mu * mu;
  const float rs = rsqrtf(var + 1e-5f);
  const float4 g  = ((const float4*)gamma)[t];
  const float4 be = ((const float4*)beta)[t];
  float4 o;
  o.x = (v.x - mu) * rs * g.x + be.x;
  o.y = (v.y - mu) * rs * g.y + be.y;
  o.z = (v.z - mu) * rs * g.z + be.z;
  o.w = (v.w - mu) * rs * g.w + be.w;
  ((float4*)(out + (size_t)row * DD))[t] = o;
}

extern "C" void kernel_launch(void* const* d_in, const int* in_sizes, int n_in,
                              void* d_out, int out_size, void* d_ws, size_t ws_size,
                              hipStream_t stream) {
  const float* x     = (const float*)d_in[0];
  const float* Ww    = (const float*)d_in[1];
  const float* Wb    = (const float*)d_in[2];
  const float* Pw    = (const float*)d_in[3];
  const float* Pb    = (const float*)d_in[4];
  const float* gamma = (const float*)d_in[5];
  const float* beta  = (const float*)d_in[6];

  float* out      = (float*)d_out;
  float* y_norm   = out;                       // 4,194,304 floats
  float* attn_out = out + (size_t)MM * DD;     // 134,217,728 floats

  char* ws = (char*)d_ws;                      // needs 50,331,648 B
  unsigned short* qb = (unsigned short*)(ws);
  unsigned short* kb = (unsigned short*)(ws + 8388608);
  unsigned short* vb = (unsigned short*)(ws + 16777216);
  unsigned short* ob = (unsigned short*)(ws + 25165824);
  float*          yw = (float*)(ws + 33554432);

  gemm_qkv<<<dim3(N3 / 128, MM / 128), 256, 0, stream>>>(x, Ww, Wb, qb, kb, vb);
  attn_kernel<<<dim3(SS / 64, BB * HH), 256, 0, stream>>>(qb, kb, vb, ob, attn_out);
  gemm_proj<<<dim3(DD / 128, MM / 128), 256, 0, stream>>>(ob, Pw, Pb, x, yw);
  ln_kernel<<<MM, 256, 0, stream>>>(yw, gamma, beta, y_norm);
}